// Round 15
// baseline (887.593 us; speedup 1.0000x reference)
//
#include <hip/hip_runtime.h>
#include <hip/hip_bf16.h>

#define D 256
#define TE 64          // messages per tile
#define NB 128         // output cols per block (colhalf)
#define BK 64          // K-chunk
#define NCHUNK 12      // 4 groups x [E | E*H | H]
#define LEAKY 0.01f
#define EPS 1e-5f

typedef float f32x4 __attribute__((ext_vector_type(4)));
typedef short s16x8 __attribute__((ext_vector_type(8)));

__device__ __forceinline__ unsigned short f2bf(float f){
  union { float f; unsigned int u; } v; v.f = f;
  unsigned int u = v.u;
  return (unsigned short)((u + 0x7fffu + ((u >> 16) & 1u)) >> 16);
}
// HW pack: D.lo = bf16(lo), D.hi = bf16(hi), RNE — 1 VALU op.
__device__ __forceinline__ unsigned int cvtpk(float lo, float hi){
  unsigned int r;
  asm("v_cvt_pk_bf16_f32 %0, %1, %2" : "=v"(r) : "v"(lo), "v"(hi));
  return r;
}

// Fragment-major bf16 image of folded weights (R12-proven layout), per
// (dir, colhalf): tile t = (dir*2+h)*12 + c (16 KB each); within: [ks][j][lane][e]
// col = h*128 + j*16 + (lane&15); k_local = ks*32 + (lane>>4)*8 + e; x = g*64+k_local.
// A wave's B-fragment load is 64 lanes x 16B CONTIGUOUS (1 KB).
__global__ void prep_w(const float* __restrict__ Wf, const float* __restrict__ Wb,
                       unsigned short* __restrict__ Wimg)
{
  int i = blockIdx.x * 256 + threadIdx.x;       // 2*2*12*8192 = 393216
  int inner = i & 8191;
  int t = i >> 13;                              // (dir*2+h)*12 + c
  int c = t % 12;
  int q = t / 12;
  int dir = q >> 1, h = q & 1;
  int g = c / 3, part = c - g * 3;
  int e    = inner & 7;
  int lane = (inner >> 3) & 63;
  int j    = (inner >> 9) & 7;
  int ks   = inner >> 12;
  int kloc = ks * 32 + (lane >> 4) * 8 + e;
  int x = g * 64 + kloc;                        // original feature index
  int col = h * NB + j * 16 + (lane & 15);
  const float* row = (dir ? Wb : Wf) + (long)col * (4 * D);
  // raw = [Hh | E | Hh+E | Hh*E]:
  float v;
  if (part == 0)      v = row[256 + x] + row[512 + x];   // E coeff
  else if (part == 1) v = row[768 + x];                  // Hh*E coeff
  else                v = row[x] + row[512 + x];         // Hh coeff
  Wimg[(size_t)t * 8192 + inner] = f2bf(v);
}

// H f32 -> bf16 copy (25 MB, L2/L3-resident) for per-lane H-fragment gathers.
__global__ void castH(const float* __restrict__ H, unsigned short* __restrict__ Hbf,
                      int n8)
{
  int i = blockIdx.x * 256 + threadIdx.x;
  if (i >= n8) return;
  const float4* s = (const float4*)H + (size_t)i * 2;
  float4 a = s[0], b = s[1];
  uint4 w;
  w.x = cvtpk(a.x, a.y); w.y = cvtpk(a.z, a.w);
  w.z = cvtpk(b.x, b.y); w.w = cvtpk(b.z, b.w);
  ((uint4*)Hbf)[i] = w;
}

// Per-dir dst histogram: cnt[0..n) = fwd (dst=tail), cnt[n..2n) = back (dst=head)
__global__ void count2(const int* __restrict__ ht, int* __restrict__ cnt,
                       int n_edges, int n_nodes)
{
  int e = blockIdx.x * 256 + threadIdx.x;
  if (e < n_edges){
    atomicAdd(&cnt[ht[2*e+1]], 1);
    atomicAdd(&cnt[n_nodes + ht[2*e]], 1);
  }
}

__global__ void scan_sums(const int* __restrict__ cnt, int* __restrict__ bsum, int N2)
{
  int t = threadIdx.x, b = blockIdx.x;
  int i = b * 1024 + t;
  int v = (i < N2) ? cnt[i] : 0;
  #pragma unroll
  for (int o = 32; o > 0; o >>= 1) v += __shfl_down(v, o);
  __shared__ int red[16];
  int lane = t & 63, wv = t >> 6;
  if (lane == 0) red[wv] = v;
  __syncthreads();
  if (t == 0){ int s = 0; for (int k = 0; k < 16; ++k) s += red[k]; bsum[b] = s; }
}

__global__ void scan_bases(const int* __restrict__ bsum, int* __restrict__ bases, int nb)
{
  if (threadIdx.x == 0 && blockIdx.x == 0){
    int a = 0;
    for (int k = 0; k < nb; ++k){ bases[k] = a; a += bsum[k]; }
  }
}

__global__ void scan_off(const int* __restrict__ cnt, const int* __restrict__ bases,
                         int* __restrict__ off, int N2)
{
  int t = threadIdx.x, b = blockIdx.x;
  int i = b * 1024 + t;
  int v = (i < N2) ? cnt[i] : 0;
  int lane = t & 63, wv = t >> 6;
  int x = v;
  #pragma unroll
  for (int o = 1; o < 64; o <<= 1){ int y = __shfl_up(x, o); if (lane >= o) x += y; }
  __shared__ int ws[16];
  if (lane == 63) ws[wv] = x;
  __syncthreads();
  if (t == 0){ int a = 0; for (int k = 0; k < 16; ++k){ int tmp = ws[k]; ws[k] = a; a += tmp; } }
  __syncthreads();
  if (i < N2) off[i] = bases[b] + ws[wv] + x - v;
}

// Build dst-sorted lists: positions [0,NE) = fwd sorted by tail, [NE,2NE) = back by head.
__global__ void scatter_msgs(const int* __restrict__ ht, const int* __restrict__ off,
                             int* __restrict__ cursor, int* __restrict__ perm,
                             int* __restrict__ dstS, int* __restrict__ hS,
                             int n_edges, int n_nodes)
{
  int m = blockIdx.x * 256 + threadIdx.x;
  if (m >= 2 * n_edges) return;
  int e  = (m < n_edges) ? m : m - n_edges;
  int hd = ht[2*e], tl = ht[2*e+1];
  int dst = (m < n_edges) ? tl : hd;
  int oth = (m < n_edges) ? hd : tl;
  int idx = ((m < n_edges) ? 0 : n_nodes) + dst;
  int pos = off[idx] + atomicAdd(&cursor[idx], 1);
  perm[pos] = e; dstS[pos] = dst; hS[pos] = oth;
}

// Barrier-free K-loop: E and E*H parts precomputed ONCE into read-only LDS
// regions (prologue); H parts gathered per-lane from bf16 H (L2-resident);
// B in registers (fragment-major image). 3 barriers total per block.
__global__ __launch_bounds__(512, 4) void edge_gemm(
    const float* __restrict__ H, const float* __restrict__ E,
    const unsigned short* __restrict__ Hbf,
    const int* __restrict__ perm, const int* __restrict__ dstS,
    const int* __restrict__ hS, const unsigned short* __restrict__ Wimg,
    float* __restrict__ agg, int n_edges, int n_nodes)
{
  __shared__ char smem[65536];     // loop: E[4][8K] @0, prod[4][8K] @32K
                                   // epilogue: Cs(32K) @0, sDst @32768

  // Bijective XCD-chunked swizzle: 4 q-blocks of a tile on the same XCD.
  const int nwg  = gridDim.x;
  const int orig = blockIdx.x;
  const int xcd  = orig & 7;
  const int lq = nwg >> 3, lr = nwg & 7;
  const int L = (xcd < lr ? xcd * (lq + 1) : lr * (lq + 1) + (xcd - lr) * lq)
                + (orig >> 3);
  const int tile = L >> 2;
  const int dir  = (L >> 1) & 1;
  const int h    = L & 1;
  const int pos0 = tile * TE;      // within dir-list

  const int tid  = threadIdx.x;
  const int lane = tid & 63;
  const int wave = tid >> 6;      // 0..7
  const int rlo  = lane & 15;
  const int khi  = lane >> 4;
  const int wm = wave >> 2;       // 0..1: 32-row slab
  const int wn = wave & 3;        // 0..3: 32-col slab

  // ---- Prologue: gather f32 E/H rows; build E and E*H LDS regions ----
  {
    const int prow = tid >> 3;    // 0..63
    const int seg  = tid & 7;     // 32-col segment
    int rp = pos0 + prow;
    int gpos = dir * n_edges + (rp >= n_edges ? n_edges - 1 : rp);
    const float* ef32 = E + (long)perm[gpos] * D + seg * 32;
    const float* hf32 = H + (long)hS[gpos] * D + seg * 32;
    float4 ev[8], hv[8];
    #pragma unroll
    for (int u = 0; u < 8; ++u){
      ev[u] = *(const float4*)(ef32 + u * 4);
      hv[u] = *(const float4*)(hf32 + u * 4);
    }
    const int g0  = seg >> 1;
    const int cbb = (seg & 1) * 4;
    #pragma unroll
    for (int u = 0; u < 4; ++u){
      float4 e0 = ev[2*u], e1 = ev[2*u+1], h0 = hv[2*u], h1 = hv[2*u+1];
      uint4 we;
      we.x = cvtpk(e0.x, e0.y); we.y = cvtpk(e0.z, e0.w);
      we.z = cvtpk(e1.x, e1.y); we.w = cvtpk(e1.z, e1.w);
      uint4 wp;
      wp.x = cvtpk(e0.x*h0.x, e0.y*h0.y); wp.y = cvtpk(e0.z*h0.z, e0.w*h0.w);
      wp.z = cvtpk(e1.x*h1.x, e1.y*h1.y); wp.w = cvtpk(e1.z*h1.z, e1.w*h1.w);
      int boff = (prow * 128 + (cbb + u) * 16) ^ ((prow & 7) << 4);
      *(uint4*)(&smem[g0 * 8192 + boff]) = we;
      *(uint4*)(&smem[32768 + g0 * 8192 + boff]) = wp;
    }
  }

  // Per-lane H row pointers for direct H-fragment gathers (part 2 chunks).
  const char* hrp0; const char* hrp1;
  {
    int row0 = wm * 32 + 0 * 16 + rlo;
    int row1 = wm * 32 + 1 * 16 + rlo;
    int rp0 = pos0 + row0, rp1 = pos0 + row1;
    int gp0 = dir * n_edges + (rp0 >= n_edges ? n_edges - 1 : rp0);
    int gp1 = dir * n_edges + (rp1 >= n_edges ? n_edges - 1 : rp1);
    hrp0 = (const char*)(Hbf + (long)hS[gp0] * D);
    hrp1 = (const char*)(Hbf + (long)hS[gp1] * D);
  }

  const char* wqB = (const char*)Wimg + (size_t)(dir * 2 + h) * NCHUNK * 16384
                    + lane * 16;

  f32x4 acc[2][2];
  #pragma unroll
  for (int mi = 0; mi < 2; ++mi)
    #pragma unroll
    for (int ni = 0; ni < 2; ++ni)
      acc[mi][ni] = (f32x4){0.f, 0.f, 0.f, 0.f};

  s16x8 bA[4], bB[4];             // B frag dbuf: chunk c uses (c&1)?bB:bA

  // 4 coalesced 16B loads: B frags (ks 0/1) x (ni 0/1) for this wave's 32 cols.
  #define LOAD_B(c, dst_) {                                                  \
    const char* bb = wqB + (size_t)(c) * 16384;                              \
    dst_[0] = *(const s16x8*)(bb + (wn * 2 + 0) * 1024);                     \
    dst_[1] = *(const s16x8*)(bb + (wn * 2 + 1) * 1024);                     \
    dst_[2] = *(const s16x8*)(bb + 8192 + (wn * 2 + 0) * 1024);              \
    dst_[3] = *(const s16x8*)(bb + 8192 + (wn * 2 + 1) * 1024);              \
  }

  LOAD_B(0, bA);
  __syncthreads();                 // E/prod regions ready; loop is barrier-free

  #pragma unroll
  for (int c = 0; c < NCHUNK; ++c){
    const int g = c / 3, part = c % 3;
    if (c + 1 < NCHUNK){
      if (c & 1) { LOAD_B(c + 1, bA); } else { LOAD_B(c + 1, bB); }
    }
    #pragma unroll
    for (int ks = 0; ks < 2; ++ks){
      const int kb = (ks * 32 + khi * 8) * 2;
      s16x8 af[2];
      if (part == 2){
        af[0] = *(const s16x8*)(hrp0 + g * 128 + kb);
        af[1] = *(const s16x8*)(hrp1 + g * 128 + kb);
      } else {
        const char* Asrc = smem + part * 32768 + g * 8192;
        #pragma unroll
        for (int mi = 0; mi < 2; ++mi){
          int row = wm * 32 + mi * 16 + rlo;
          af[mi] = *(const s16x8*)(Asrc + ((row * 128 + kb) ^ ((row & 7) << 4)));
        }
      }
      #pragma unroll
      for (int mi = 0; mi < 2; ++mi)
        #pragma unroll
        for (int ni = 0; ni < 2; ++ni)
          acc[mi][ni] = __builtin_amdgcn_mfma_f32_16x16x32_bf16(
              af[mi], (c & 1) ? bB[ks * 2 + ni] : bA[ks * 2 + ni],
              acc[mi][ni], 0, 0, 0);
    }
  }
  #undef LOAD_B

  // ---- Epilogue: C -> LDS, segmented run-reduce over dst-sorted rows ----
  __syncthreads();                 // all E/prod reads done; smem reusable
  float* Cs = (float*)smem;        // [64][128], bank-rotated by row
  #pragma unroll
  for (int mi = 0; mi < 2; ++mi)
    #pragma unroll
    for (int ni = 0; ni < 2; ++ni)
      #pragma unroll
      for (int r = 0; r < 4; ++r){
        int row = wm * 32 + mi * 16 + khi * 4 + r;
        int col = wn * 32 + ni * 16 + rlo;
        int cw = (col + ((row & 7) << 2)) & 127;
        Cs[row * 128 + cw] = acc[mi][ni][r];
      }
  int* sD = (int*)(smem + 32768);
  if (tid < TE){
    int rp = pos0 + tid;
    sD[tid] = (rp < n_edges) ? dstS[dir * n_edges + rp] : 0x7fffffff;
  }
  __syncthreads();

  {
    const int col = tid & 127;
    const int q   = tid >> 7;          // 4 row-quarters of 16
    int r0 = q << 4;
    if (q > 0 && sD[r0] == sD[r0 - 1]){
      int pd = sD[r0 - 1];
      int rcap = (q << 4) + 16;
      while (r0 < rcap && sD[r0] == pd) r0++;
    }
    const int rend = (q << 4) + 16;
    for (int r = r0; r < rend; ){
      int d = sD[r];
      float s = 0.f;
      int rr = r;
      while (rr < TE && sD[rr] == d){
        s += Cs[rr * 128 + ((col + ((rr & 7) << 2)) & 127)];
        rr++;
      }
      if (d < n_nodes)
        atomicAdd(agg + (long)d * D + h * NB + col, s);
      r = rr;
    }
  }
}

__global__ __launch_bounds__(256) void finish(
    const float* __restrict__ agg, const int* __restrict__ cnt_i,
    const float* __restrict__ H, const float* __restrict__ bias_f,
    const float* __restrict__ bias_b, const float* __restrict__ gamma,
    const float* __restrict__ beta, float* __restrict__ out, int n_nodes)
{
  const int n = blockIdx.x;
  const int j = threadIdx.x;
  int cf = cnt_i[n], cb = cnt_i[n_nodes + n];
  float c = (float)(cf + cb); c = c < 1.f ? 1.f : c;
  float a = (agg[(long)n * D + j] + (float)cf * bias_f[j] + (float)cb * bias_b[j]) / c;
  float x = (a > 0.f ? a : LEAKY * a) + H[(long)n * D + j];
  float s1 = x, s2 = x * x;
  #pragma unroll
  for (int off = 32; off > 0; off >>= 1){
    s1 += __shfl_xor(s1, off);
    s2 += __shfl_xor(s2, off);
  }
  __shared__ float rs[8];
  if ((j & 63) == 0){ rs[j >> 6] = s1; rs[4 + (j >> 6)] = s2; }
  __syncthreads();
  float t1 = rs[0] + rs[1] + rs[2] + rs[3];
  float t2 = rs[4] + rs[5] + rs[6] + rs[7];
  float mu = t1 * (1.f / D);
  float var = t2 * (1.f / D) - mu * mu;
  float r = rsqrtf(var + EPS);
  out[(long)n * D + j] = (x - mu) * r * gamma[j] + beta[j];
}

extern "C" void kernel_launch(void* const* d_in, const int* in_sizes, int n_in,
                              void* d_out, int out_size, void* d_ws, size_t ws_size,
                              hipStream_t stream)
{
  const float* H      = (const float*)d_in[0];
  const float* E      = (const float*)d_in[1];
  const int*   ht     = (const int*)d_in[2];
  const float* W_fwd  = (const float*)d_in[3];
  const float* b_fwd  = (const float*)d_in[4];
  const float* W_back = (const float*)d_in[5];
  const float* b_back = (const float*)d_in[6];
  const float* gamma  = (const float*)d_in[7];
  const float* beta   = (const float*)d_in[8];
  float* out = (float*)d_out;

  const int n_nodes = in_sizes[0] / D;
  const int n_edges = in_sizes[2] / 2;
  const int N2 = 2 * n_nodes;
  const int NM = 2 * n_edges;

  char* p = (char*)d_ws;
  float* agg    = (float*)p;  p += (size_t)n_nodes * D * 4;
  int*   cnt_i  = (int*)p;    p += (size_t)N2 * 4;
  int*   cursor = (int*)p;    p += (size_t)N2 * 4;
  size_t zbytes = (size_t)(p - (char*)d_ws);          // agg + cnt + cursor
  int*   off    = (int*)p;    p += (size_t)N2 * 4;
  int*   bsum   = (int*)p;    p += 128 * 4;
  int*   bases  = (int*)p;    p += 128 * 4;
  int*   perm   = (int*)p;    p += (size_t)NM * 4;
  int*   dstS   = (int*)p;    p += (size_t)NM * 4;
  int*   hS     = (int*)p;    p += (size_t)NM * 4;
  unsigned short* Hbf = (unsigned short*)p; p += (size_t)n_nodes * D * 2;
  p = (char*)(((size_t)p + 255) & ~(size_t)255);
  unsigned short* Wimg = (unsigned short*)p;

  const int nscan = (N2 + 1023) / 1024;

  hipMemsetAsync(d_ws, 0, zbytes, stream);
  prep_w<<<(2 * 2 * NCHUNK * 8192) / 256, 256, 0, stream>>>(W_fwd, W_back, Wimg);
  castH<<<(n_nodes * D / 8 + 255) / 256, 256, 0, stream>>>(H, Hbf, n_nodes * D / 8);
  count2<<<(n_edges + 255) / 256, 256, 0, stream>>>(ht, cnt_i, n_edges, n_nodes);
  scan_sums<<<nscan, 1024, 0, stream>>>(cnt_i, bsum, N2);
  scan_bases<<<1, 64, 0, stream>>>(bsum, bases, nscan);
  scan_off<<<nscan, 1024, 0, stream>>>(cnt_i, bases, off, N2);
  scatter_msgs<<<(NM + 255) / 256, 256, 0, stream>>>(ht, off, cursor, perm, dstS, hS,
                                                     n_edges, n_nodes);
  const int ntiles = (n_edges + TE - 1) / TE;
  edge_gemm<<<ntiles * 4, 512, 0, stream>>>(H, E, Hbf, perm, dstS, hS, Wimg, agg,
                                            n_edges, n_nodes);
  finish<<<n_nodes, 256, 0, stream>>>(agg, cnt_i, H, b_fwd, b_back, gamma, beta,
                                      out, n_nodes);
}

// Round 16
// 366.452 us; speedup vs baseline: 2.4221x; 2.4221x over previous
//
#include <hip/hip_runtime.h>
#include <hip/hip_bf16.h>

#define D 256
#define NB 128         // output cols per GEMM block (colhalf)
#define BK 64          // K-chunk
#define NCK 24         // K = 2 dirs x 768 = 1536 -> 24 chunks
#define NPB 64         // nodes per aggregation block
#define LEAKY 0.01f
#define EPS 1e-5f

typedef float f32x4 __attribute__((ext_vector_type(4)));
typedef short s16x8 __attribute__((ext_vector_type(8)));

#define GLL16(g, l) __builtin_amdgcn_global_load_lds(                      \
    (const __attribute__((address_space(1))) unsigned int*)(g),            \
    (__attribute__((address_space(3))) unsigned int*)(l), 16, 0, 0)

__device__ __forceinline__ unsigned short f2bf(float f){
  union { float f; unsigned int u; } v; v.f = f;
  unsigned int u = v.u;
  return (unsigned short)((u + 0x7fffu + ((u >> 16) & 1u)) >> 16);
}

// Pre-swizzled bf16 image of stacked folded weights.
// K axis (1536): [dir=0: E(256)|E*H(256)|H(256) | dir=1: same].
// Image tile t = h*24 + c (16 KB): boff = (j*128 + k*2) ^ ((j&7)<<4),
// j = col within half (0..127), k = local K (0..63).
__global__ void prep_w(const float* __restrict__ Wf, const float* __restrict__ Wb,
                       unsigned short* __restrict__ Wimg)
{
  int i = blockIdx.x * 256 + threadIdx.x;       // 2*24*128*64 = 393216
  int inner = i & 8191;                         // j*64 + k
  int t = i >> 13;                              // h*24 + c
  int c = t % 24;
  int h = t / 24;
  int j = inner >> 6, k = inner & 63;
  int kg  = c * 64 + k;                         // global K index 0..1535
  int dir = kg / 768;
  int kl  = kg - dir * 768;
  int part = kl >> 8, x = kl & 255;
  const float* row = (dir ? Wb : Wf) + (long)(h * NB + j) * (4 * D);
  // raw = [Hh | E | Hh+E | Hh*E]:
  float v;
  if (part == 0)      v = row[256 + x] + row[512 + x];   // E coeff
  else if (part == 1) v = row[768 + x];                  // Hh*E coeff
  else                v = row[x] + row[512 + x];         // Hh coeff
  int boff = (j * 128 + k * 2) ^ ((j & 7) << 4);
  *(unsigned short*)((char*)Wimg + (size_t)t * 16384 + boff) = f2bf(v);
}

// Per-dir dst histogram: cnt[0..n) = fwd (dst=tail), cnt[n..2n) = back (dst=head)
__global__ void count2(const int* __restrict__ ht, int* __restrict__ cnt,
                       int n_edges, int n_nodes)
{
  int e = blockIdx.x * 256 + threadIdx.x;
  if (e < n_edges){
    atomicAdd(&cnt[ht[2*e+1]], 1);
    atomicAdd(&cnt[n_nodes + ht[2*e]], 1);
  }
}

__global__ void scan_sums(const int* __restrict__ cnt, int* __restrict__ bsum, int N2)
{
  int t = threadIdx.x, b = blockIdx.x;
  int i = b * 1024 + t;
  int v = (i < N2) ? cnt[i] : 0;
  #pragma unroll
  for (int o = 32; o > 0; o >>= 1) v += __shfl_down(v, o);
  __shared__ int red[16];
  int lane = t & 63, wv = t >> 6;
  if (lane == 0) red[wv] = v;
  __syncthreads();
  if (t == 0){ int s = 0; for (int k = 0; k < 16; ++k) s += red[k]; bsum[b] = s; }
}

__global__ void scan_bases(const int* __restrict__ bsum, int* __restrict__ bases, int nb)
{
  if (threadIdx.x == 0 && blockIdx.x == 0){
    int a = 0;
    for (int k = 0; k < nb; ++k){ bases[k] = a; a += bsum[k]; }
  }
}

__global__ void scan_off(const int* __restrict__ cnt, const int* __restrict__ bases,
                         int* __restrict__ off, int N2)
{
  int t = threadIdx.x, b = blockIdx.x;
  int i = b * 1024 + t;
  int v = (i < N2) ? cnt[i] : 0;
  int lane = t & 63, wv = t >> 6;
  int x = v;
  #pragma unroll
  for (int o = 1; o < 64; o <<= 1){ int y = __shfl_up(x, o); if (lane >= o) x += y; }
  __shared__ int ws[16];
  if (lane == 63) ws[wv] = x;
  __syncthreads();
  if (t == 0){ int a = 0; for (int k = 0; k < 16; ++k){ int tmp = ws[k]; ws[k] = a; a += tmp; } }
  __syncthreads();
  if (i < N2) off[i] = bases[b] + ws[wv] + x - v;
}

// Build dst-sorted lists: positions [0,NE) = fwd sorted by tail, [NE,2NE) = back by head.
__global__ void scatter_msgs(const int* __restrict__ ht, const int* __restrict__ off,
                             int* __restrict__ cursor, int* __restrict__ perm,
                             int* __restrict__ hS, int n_edges, int n_nodes)
{
  int m = blockIdx.x * 256 + threadIdx.x;
  if (m >= 2 * n_edges) return;
  int e  = (m < n_edges) ? m : m - n_edges;
  int hd = ht[2*e], tl = ht[2*e+1];
  int dst = (m < n_edges) ? tl : hd;
  int oth = (m < n_edges) ? hd : tl;
  int idx = ((m < n_edges) ? 0 : n_nodes) + dst;
  int pos = off[idx] + atomicAdd(&cursor[idx], 1);
  perm[pos] = e; hS[pos] = oth;
}

// Segment-sum folded features per (node, dir): S[n][dir*768 + band*256 + t].
// Block owns NPB whole nodes -> zero atomics, plain bf16 stores, no memset.
// Thread t owns column t of each band; E/H row reads are fully coalesced.
__global__ __launch_bounds__(256, 8) void aggregate(
    const float* __restrict__ H, const float* __restrict__ E,
    const int* __restrict__ perm, const int* __restrict__ hS,
    const int* __restrict__ off, const int* __restrict__ cnt_i,
    unsigned short* __restrict__ S, int n_edges, int n_nodes)
{
  const int t   = threadIdx.x;
  const int dir = blockIdx.x & 1;
  const int b   = blockIdx.x >> 1;
  const int n0  = b * NPB;

  for (int i = 0; i < NPB; ++i){
    int n = n0 + i;
    if (n >= n_nodes) break;
    int idx  = dir * n_nodes + n;
    int base = off[idx];
    int cn   = cnt_i[idx];
    float s0 = 0.f, s1 = 0.f, s2 = 0.f;
    int k = 0;
    for (; k + 1 < cn; k += 2){
      int p0 = base + k, p1 = p0 + 1;
      int e0 = perm[p0], h0 = hS[p0];
      int e1 = perm[p1], h1 = hS[p1];
      float ev0 = E[(size_t)e0 * D + t];
      float hv0 = H[(size_t)h0 * D + t];
      float ev1 = E[(size_t)e1 * D + t];
      float hv1 = H[(size_t)h1 * D + t];
      s0 += ev0 + ev1;
      s1 += ev0 * hv0 + ev1 * hv1;
      s2 += hv0 + hv1;
    }
    if (k < cn){
      int p0 = base + k;
      int e0 = perm[p0], h0 = hS[p0];
      float ev0 = E[(size_t)e0 * D + t];
      float hv0 = H[(size_t)h0 * D + t];
      s0 += ev0; s1 += ev0 * hv0; s2 += hv0;
    }
    size_t o = (size_t)n * 1536 + dir * 768 + t;
    S[o]       = f2bf(s0);
    S[o + 256] = f2bf(s1);
    S[o + 512] = f2bf(s2);
  }
}

// Dense GEMM: agg[n][0..256) = S[n][0..1536) @ Wimg (stacked dirs).
// R7-proven anatomy: glds-staged A (pre-swizzled per-lane SOURCE addr,
// linear LDS dest) + glds B from pre-swizzled image; 2-phase barrier loop;
// plain coalesced C stores (no atomics, no scatter).
__global__ __launch_bounds__(512, 4) void node_gemm(
    const unsigned short* __restrict__ S, const unsigned short* __restrict__ Wimg,
    float* __restrict__ agg, int n_nodes)
{
  __shared__ char smem[65536];
  char (*sAl)[16384] = (char(*)[16384])smem;            // 128 rows x 64 k
  char (*sBl)[16384] = (char(*)[16384])(smem + 32768);  // 128 cols x 64 k

  const int bid = blockIdx.x;
  const int h   = bid & 1;
  const int n0  = (bid >> 1) * 128;

  const int tid  = threadIdx.x;
  const int lane = tid & 63;
  const int wave = tid >> 6;      // 0..7

  const char* wq = (const char*)Wimg + (size_t)h * NCK * 16384;
  const char* Sb = (const char*)S;

  f32x4 acc[4][2];
  #pragma unroll
  for (int mi = 0; mi < 4; ++mi)
    #pragma unroll
    for (int ni = 0; ni < 2; ++ni)
      acc[mi][ni] = (f32x4){0.f, 0.f, 0.f, 0.f};

  const int rlo = lane & 15;
  const int khi = lane >> 4;
  const int wm = wave >> 2;       // 0..1: 64-row slab
  const int wn = wave & 3;        // 0..3: 32-col slab

  // Wave stages rows [w*8, w*8+8) and [64+w*8, ...): lane -> row w*8+(l>>3),
  // k-unit (l&7). Source k-unit XOR'd by (slotrow&7) = (l>>3) so the linear
  // LDS image is the swizzled tile (m173: pre-swizzled source, linear dest).
  const int arow = wave * 8 + (lane >> 3);
  const int aunit = ((lane & 7) ^ (lane >> 3)) * 16;
  const size_t an0 = (size_t)((n0 + arow      < n_nodes) ? n0 + arow      : n_nodes - 1);
  const size_t an1 = (size_t)((n0 + 64 + arow < n_nodes) ? n0 + 64 + arow : n_nodes - 1);

  #define STAGE_A(c, buf) {                                                  \
    const char* s0 = Sb + an0 * 3072 + (size_t)(c) * 128 + aunit;            \
    const char* s1 = Sb + an1 * 3072 + (size_t)(c) * 128 + aunit;            \
    char* d = &sAl[buf][wave * 1024];                                        \
    GLL16(s0, d);                                                            \
    GLL16(s1, d + 8192);                                                     \
  }

  #define STAGE_B(c, buf) {                                                  \
    const char* srcb = wq + (size_t)(c) * 16384 + wave * 2048 + lane * 16;   \
    char* db = &sBl[buf][wave * 2048];                                       \
    GLL16(srcb,        db);                                                  \
    GLL16(srcb + 1024, db + 1024);                                           \
  }

  STAGE_A(0, 0);
  STAGE_B(0, 0);
  __syncthreads();

  #pragma unroll
  for (int c = 0; c < NCK; ++c){
    const int cur = c & 1;
    if (c + 1 < NCK){
      STAGE_A(c + 1, cur ^ 1);
      STAGE_B(c + 1, cur ^ 1);
    }
    #pragma unroll
    for (int ks = 0; ks < 2; ++ks){
      const int kb = (ks * 32 + khi * 8) * 2;
      s16x8 af[4], bfr[2];
      #pragma unroll
      for (int mi = 0; mi < 4; ++mi){
        int row = wm * 64 + mi * 16 + rlo;
        af[mi] = *(const s16x8*)(&sAl[cur][(row * 128 + kb) ^ ((row & 7) << 4)]);
      }
      #pragma unroll
      for (int ni = 0; ni < 2; ++ni){
        int col = wn * 32 + ni * 16 + rlo;
        bfr[ni] = *(const s16x8*)(&sBl[cur][(col * 128 + kb) ^ ((col & 7) << 4)]);
      }
      #pragma unroll
      for (int mi = 0; mi < 4; ++mi)
        #pragma unroll
        for (int ni = 0; ni < 2; ++ni)
          acc[mi][ni] = __builtin_amdgcn_mfma_f32_16x16x32_bf16(
              af[mi], bfr[ni], acc[mi][ni], 0, 0, 0);
    }
    if (c + 1 < NCK) __syncthreads();
  }
  #undef STAGE_A
  #undef STAGE_B

  // Plain coalesced C stores.
  #pragma unroll
  for (int ni = 0; ni < 2; ++ni){
    const int col = h * NB + wn * 32 + ni * 16 + rlo;
    #pragma unroll
    for (int mi = 0; mi < 4; ++mi){
      #pragma unroll
      for (int r = 0; r < 4; ++r){
        int n = n0 + wm * 64 + mi * 16 + khi * 4 + r;
        if (n < n_nodes)
          agg[(size_t)n * D + col] = acc[mi][ni][r];
      }
    }
  }
}

__global__ __launch_bounds__(256) void finish(
    const float* __restrict__ agg, const int* __restrict__ cnt_i,
    const float* __restrict__ H, const float* __restrict__ bias_f,
    const float* __restrict__ bias_b, const float* __restrict__ gamma,
    const float* __restrict__ beta, float* __restrict__ out, int n_nodes)
{
  const int n = blockIdx.x;
  const int j = threadIdx.x;
  int cf = cnt_i[n], cb = cnt_i[n_nodes + n];
  float c = (float)(cf + cb); c = c < 1.f ? 1.f : c;
  float a = (agg[(size_t)n * D + j] + (float)cf * bias_f[j] + (float)cb * bias_b[j]) / c;
  float x = (a > 0.f ? a : LEAKY * a) + H[(size_t)n * D + j];
  float s1 = x, s2 = x * x;
  #pragma unroll
  for (int off = 32; off > 0; off >>= 1){
    s1 += __shfl_xor(s1, off);
    s2 += __shfl_xor(s2, off);
  }
  __shared__ float rs[8];
  if ((j & 63) == 0){ rs[j >> 6] = s1; rs[4 + (j >> 6)] = s2; }
  __syncthreads();
  float t1 = rs[0] + rs[1] + rs[2] + rs[3];
  float t2 = rs[4] + rs[5] + rs[6] + rs[7];
  float mu = t1 * (1.f / D);
  float var = t2 * (1.f / D) - mu * mu;
  float r = rsqrtf(var + EPS);
  out[(size_t)n * D + j] = (x - mu) * r * gamma[j] + beta[j];
}

extern "C" void kernel_launch(void* const* d_in, const int* in_sizes, int n_in,
                              void* d_out, int out_size, void* d_ws, size_t ws_size,
                              hipStream_t stream)
{
  const float* H      = (const float*)d_in[0];
  const float* E      = (const float*)d_in[1];
  const int*   ht     = (const int*)d_in[2];
  const float* W_fwd  = (const float*)d_in[3];
  const float* b_fwd  = (const float*)d_in[4];
  const float* W_back = (const float*)d_in[5];
  const float* b_back = (const float*)d_in[6];
  const float* gamma  = (const float*)d_in[7];
  const float* beta   = (const float*)d_in[8];
  float* out = (float*)d_out;

  const int n_nodes = in_sizes[0] / D;
  const int n_edges = in_sizes[2] / 2;
  const int N2 = 2 * n_nodes;
  const int NM = 2 * n_edges;

  char* p = (char*)d_ws;
  float* agg    = (float*)p;  p += (size_t)n_nodes * D * 4;
  int*   cnt_i  = (int*)p;    p += (size_t)N2 * 4;
  int*   cursor = (int*)p;    p += (size_t)N2 * 4;
  int*   off    = (int*)p;    p += (size_t)N2 * 4;
  int*   bsum   = (int*)p;    p += 128 * 4;
  int*   bases  = (int*)p;    p += 128 * 4;
  int*   perm   = (int*)p;    p += (size_t)NM * 4;
  int*   hS     = (int*)p;    p += (size_t)NM * 4;
  unsigned short* S = (unsigned short*)p; p += (size_t)n_nodes * 1536 * 2;
  p = (char*)(((size_t)p + 255) & ~(size_t)255);
  unsigned short* Wimg = (unsigned short*)p;

  const int nscan = (N2 + 1023) / 1024;

  // zero cnt_i + cursor only (contiguous)
  hipMemsetAsync(cnt_i, 0, (size_t)N2 * 2 * 4, stream);
  prep_w<<<(2 * NCK * NB * BK) / 256, 256, 0, stream>>>(W_fwd, W_back, Wimg);
  count2<<<(n_edges + 255) / 256, 256, 0, stream>>>(ht, cnt_i, n_edges, n_nodes);
  scan_sums<<<nscan, 1024, 0, stream>>>(cnt_i, bsum, N2);
  scan_bases<<<1, 64, 0, stream>>>(bsum, bases, nscan);
  scan_off<<<nscan, 1024, 0, stream>>>(cnt_i, bases, off, N2);
  scatter_msgs<<<(NM + 255) / 256, 256, 0, stream>>>(ht, off, cursor, perm, hS,
                                                     n_edges, n_nodes);
  const int nblk = (n_nodes + NPB - 1) / NPB;
  aggregate<<<2 * nblk, 256, 0, stream>>>(H, E, perm, hS, off, cnt_i, S,
                                          n_edges, n_nodes);
  const int nbm = (n_nodes + 127) / 128;
  node_gemm<<<nbm * 2, 512, 0, stream>>>(S, Wimg, agg, n_nodes);
  finish<<<n_nodes, 256, 0, stream>>>(agg, cnt_i, H, b_fwd, b_back, gamma, beta,
                                      out, n_nodes);
}